// Round 1
// 472.128 us; speedup vs baseline: 1.0238x; 1.0238x over previous
//
#include <hip/hip_runtime.h>

// GCNConv: out = D^-1/2 (A) D^-1/2 (X @ W) + bias,  deg = rowsum(A) + l
// N=8192, DIN=DOUT=256. A fp32 [N][N], X fp32 [N][256], W fp32 [256][256].
//
// R5 -> R6:
//  * k1 fuses rowsum with fp32->bf16 conversion of A, writing A_bf16 (128 MB)
//    in tile-major (64x64) XOR-swizzled image layout (byte = r*128 +
//    (cb ^ ((r&7)<<4))). A reads nontemporal -> A_bf16 stays L3-resident.
//  * k4 reads A_bf16 via global_load_lds (2x16B calls/wave/iter, double
//    buffer, single "vmcnt(8); s_barrier" per K-step). Halves k4's A bytes,
//    removes in-loop cvt + ds_write staging entirely.
//  * epilogue: plain stores to 4 partial buffers; new reduce kernel applies
//    d_i * (p0+p1+p2+p3) + bias. No atomics, no out memset.
// Workspace need: 32KB d | 128KB WT | 4MB ST | 32MB partials | 128MB A_bf16
//               = ~164.2 MB (1-GiB poison fills indicate a 1-GiB arena).

typedef __attribute__((ext_vector_type(8))) short short8;
typedef __attribute__((ext_vector_type(4))) float f32x4;

#define NN 8192
#define DD 256
#define KCHUNK 2048
#define BK 64
#define NITER (KCHUNK / BK)

// fp32 -> bf16 RNE (no NaN guard: inputs are finite)
__device__ inline unsigned short f2bfu(float x) {
    unsigned int u = __builtin_bit_cast(unsigned int, x);
    u += 0x7fffu + ((u >> 16) & 1u);
    return (unsigned short)(u >> 16);
}
__device__ inline unsigned int f2bf2u(float x, float y) {
    return (unsigned int)f2bfu(x) | ((unsigned int)f2bfu(y) << 16);
}
__device__ inline short8 cvt8(float4 a, float4 b) {
    union { unsigned int i[4]; short8 s; } u;
    u.i[0] = f2bf2u(a.x, a.y);
    u.i[1] = f2bf2u(a.z, a.w);
    u.i[2] = f2bf2u(b.x, b.y);
    u.i[3] = f2bf2u(b.z, b.w);
    return u.s;
}

__device__ inline void gload16(const void* g, void* l) {
    __builtin_amdgcn_global_load_lds(
        (const __attribute__((address_space(1))) unsigned int*)g,
        (__attribute__((address_space(3))) unsigned int*)l, 16, 0, 0);
}

// ---------------- k1: rowsum -> d[i]; A -> bf16 swizzled tile image --------
// 16 rows/block, 16 threads/row. Per k-iter a 16-thread row-group reads one
// 64-col tile-row (256 B contiguous) and writes its 128-B swizzled image row.
__global__ __launch_bounds__(256) void rowsum_conv(const float* __restrict__ A,
                                                   const int* __restrict__ lp,
                                                   float* __restrict__ d,
                                                   unsigned short* __restrict__ Abf) {
    const int t = threadIdx.x;
    const int rl = t >> 4;     // row within block
    const int cg = t & 15;     // 16 threads per row
    const int i = blockIdx.x * 16 + rl;
    const int ti = i >> 6;
    const int rt = i & 63;
    const int swz = (rt & 7) << 4;

    const f32x4* Ar = (const f32x4*)(A + (size_t)i * NN);
    // image base for this row: tile (ti, k) at ((ti*128 + k)*8192) bytes;
    // in-tile byte = rt*128 + ((8*cg) ^ swz)   (8 B per thread per k)
    char* tb = (char*)Abf + (size_t)ti * 128 * 8192 + rt * 128 + ((8 * cg) ^ swz);

    float s0 = 0.f, s1 = 0.f;
#pragma unroll 4
    for (int k = 0; k < 128; ++k) {
        f32x4 v = __builtin_nontemporal_load(Ar + cg + 16 * k);  // nt: keep L3 for Abf
        s0 += v[0] + v[1];
        s1 += v[2] + v[3];
        *(uint2*)(tb + (size_t)k * 8192) =
            make_uint2(f2bf2u(v[0], v[1]), f2bf2u(v[2], v[3]));
    }
    float s = s0 + s1;
#pragma unroll
    for (int off = 8; off > 0; off >>= 1) s += __shfl_down(s, off, 16);
    if (cg == 0) {
        float deg = s + (float)(*lp);
        d[i] = deg > 0.f ? rsqrtf(deg) : 0.f;
    }
}

// ---------------- k2: W^T -> bf16 ----------------------------------------
__global__ __launch_bounds__(256) void wtrans_kernel(const float* __restrict__ W,
                                                     unsigned short* __restrict__ WT) {
    __shared__ unsigned short tile[64][65];
    const int tx = threadIdx.x & 63, ty = threadIdx.x >> 6;
    const int i0 = (blockIdx.x & 3) * 64;
    const int n0 = (blockIdx.x >> 2) * 64;
#pragma unroll
    for (int r = ty; r < 64; r += 4)
        tile[r][tx] = f2bfu(W[(size_t)(i0 + r) * DD + n0 + tx]);
    __syncthreads();
#pragma unroll
    for (int r = ty; r < 64; r += 4)
        WT[(size_t)(n0 + r) * DD + i0 + tx] = tile[tx][r];
}

// ---------------- k3: S_T[n][j] = bf16(d_j * (X@W)[j][n]) ----------------
__global__ __launch_bounds__(256) void support_kernel(const float* __restrict__ X,
                                                      const unsigned short* __restrict__ WT,
                                                      const float* __restrict__ d,
                                                      unsigned short* __restrict__ ST) {
    const int j0 = blockIdx.x * 16;
    const int lane = threadIdx.x & 63;
    const int w = threadIdx.x >> 6;
    const int q = lane >> 4;
    const int l15 = lane & 15;
    const int nb = w * 64;

    f32x4 acc[4];
#pragma unroll
    for (int b = 0; b < 4; ++b) acc[b] = (f32x4)(0.f);

    const float* Xbase = X + (size_t)(j0 + l15) * DD + q * 8;
    const unsigned short* Wbase = WT + (size_t)(nb + l15) * DD + q * 8;

#pragma unroll
    for (int k0 = 0; k0 < DD; k0 += 32) {
        const float4* p = (const float4*)(Xbase + k0);
        short8 afr = cvt8(p[0], p[1]);
        short8 bfr[4];
#pragma unroll
        for (int ni = 0; ni < 4; ++ni)
            bfr[ni] = *(const short8*)(Wbase + ni * 16 * DD + k0);
#pragma unroll
        for (int ni = 0; ni < 4; ++ni)
            acc[ni] = __builtin_amdgcn_mfma_f32_16x16x32_bf16(afr, bfr[ni], acc[ni], 0, 0, 0);
    }

    const int j0r = j0 + q * 4;
    float dj[4];
#pragma unroll
    for (int r = 0; r < 4; ++r) dj[r] = d[j0r + r];
#pragma unroll
    for (int ni = 0; ni < 4; ++ni) {
        const int n = nb + ni * 16 + l15;
        unsigned int lo = f2bf2u(acc[ni][0] * dj[0], acc[ni][1] * dj[1]);
        unsigned int hi = f2bf2u(acc[ni][2] * dj[2], acc[ni][3] * dj[3]);
        *(uint2*)(ST + (size_t)n * NN + j0r) = make_uint2(lo, hi);
    }
}

// ---------------- k4: partial[kc] = A_bf16 @ S_T^T -----------------------
// M=64, N=256, BK=64, KCHUNK=2048; grid 128 mt x 4 kc = 512 blocks (2/CU).
// Per iter: vmcnt(8)+barrier (retires A(it), leaves B(it) in flight) |
// issue A(it+1) via global_load_lds into buf^1 | issue B(it+1)->regs |
// compute tile it from swizzled LDS + register B. Single barrier per iter;
// vmcnt never drains. Plain stores to partial buffer (no atomics, no d/bias).
__global__ __launch_bounds__(256) void main_gemm(const unsigned short* __restrict__ Abf,
                                                 const unsigned short* __restrict__ ST,
                                                 float* __restrict__ part) {
    __shared__ __align__(16) unsigned short Abuf[2][4096];  // 2 x 8 KB tile image

    const int mt = blockIdx.x & 127;
    const int kc = blockIdx.x >> 7;  // 0..3
    const int tid = threadIdx.x;
    const int lane = tid & 63;
    const int w = tid >> 6;
    const int q = lane >> 4;
    const int l15 = lane & 15;
    const int nb = w * 64;
    const int swz = (l15 & 7) << 4;

    // global source of this block's tiles (image layout == LDS layout)
    const char* Ag = (const char*)Abf + ((size_t)mt * 128 + kc * NITER) * 8192
                     + w * 2048 + lane * 16;
    const unsigned short* Bptr = ST + (size_t)(nb + l15) * NN + kc * KCHUNK + q * 8;

    f32x4 acc[4][4];
#pragma unroll
    for (int a = 0; a < 4; ++a)
#pragma unroll
        for (int b = 0; b < 4; ++b) acc[a][b] = (f32x4)(0.f);

    short8 bfr[2][2][4];  // [phase parity][kk2][ni]

    // ---- prologue: issue A(0) (pinned first), then B(0)
    {
        unsigned short* l0 = &Abuf[0][w * 1024];
        gload16(Ag, l0);
        gload16(Ag + 1024, l0 + 512);
    }
    __builtin_amdgcn_sched_barrier(0);
#pragma unroll
    for (int kk2 = 0; kk2 < 2; ++kk2)
#pragma unroll
        for (int ni = 0; ni < 4; ++ni)
            bfr[0][kk2][ni] = *(const short8*)(Bptr + (size_t)(ni * 16) * NN + kk2 * 32);
    __builtin_amdgcn_sched_barrier(0);

    const char* Ab0 = (const char*)&Abuf[0][0] + l15 * 128;
    const char* Ab1 = (const char*)&Abuf[1][0] + l15 * 128;

#pragma unroll 2
    for (int it = 0; it < NITER; ++it) {
        const int buf = it & 1;
        // outstanding here: A(it) x2 (oldest) + B(it) x8 -> vmcnt(8) retires A(it)
        __asm__ __volatile__("s_waitcnt vmcnt(8)\n\ts_barrier" ::: "memory");

        if (it + 1 < NITER) {  // issue A(it+1) -> buf^1 (readers of it-1 done at barrier)
            const char* gn = Ag + (size_t)(it + 1) * 8192;
            unsigned short* ln = &Abuf[buf ^ 1][w * 1024];
            gload16(gn, ln);
            gload16(gn + 1024, ln + 512);
        }
        __builtin_amdgcn_sched_barrier(0);  // pin A-issue before B-issue (vmcnt order)
        if (it + 1 < NITER) {
#pragma unroll
            for (int kk2 = 0; kk2 < 2; ++kk2)
#pragma unroll
                for (int ni = 0; ni < 4; ++ni)
                    bfr[buf ^ 1][kk2][ni] = *(const short8*)(
                        Bptr + (size_t)(ni * 16) * NN + (it + 1) * BK + kk2 * 32);
        }
        __builtin_amdgcn_sched_barrier(0);

        // compute tile it: swizzled ds_read_b128 frags + register B
        const char* Ab = buf ? Ab1 : Ab0;
#pragma unroll
        for (int kk2 = 0; kk2 < 2; ++kk2) {
            short8 afr[4];
#pragma unroll
            for (int mi = 0; mi < 4; ++mi)
                afr[mi] = *(const short8*)(Ab + mi * 2048 + ((kk2 * 64 + q * 16) ^ swz));
#pragma unroll
            for (int mi = 0; mi < 4; ++mi)
#pragma unroll
                for (int ni = 0; ni < 4; ++ni)
                    acc[mi][ni] = __builtin_amdgcn_mfma_f32_16x16x32_bf16(
                        afr[mi], bfr[buf][kk2][ni], acc[mi][ni], 0, 0, 0);
        }
    }

    // epilogue: plain stores of raw partials (d_i & bias applied in reduce)
    float* P = part + (size_t)kc * NN * DD;
#pragma unroll
    for (int mi = 0; mi < 4; ++mi) {
        const int r0 = mt * 64 + mi * 16 + q * 4;
#pragma unroll
        for (int ni = 0; ni < 4; ++ni) {
            const int n = nb + ni * 16 + l15;
#pragma unroll
            for (int rr = 0; rr < 4; ++rr)
                P[(size_t)(r0 + rr) * DD + n] = acc[mi][ni][rr];
        }
    }
}

// ---------------- k5: out = d_i * (p0+p1+p2+p3) + bias -------------------
__global__ __launch_bounds__(256) void reduce_kernel(const float* __restrict__ part,
                                                     const float* __restrict__ d,
                                                     const float* __restrict__ bias,
                                                     float* __restrict__ out) {
    const int idx = blockIdx.x * 256 + threadIdx.x;  // 0..524287
    const int i = idx >> 6;                          // row
    const int c4 = (idx & 63) << 2;                  // col (floats)
    const size_t off = (size_t)i * DD + c4;
    const size_t stride = (size_t)NN * DD;
    f32x4 s = *(const f32x4*)(part + off);
    s += *(const f32x4*)(part + stride + off);
    s += *(const f32x4*)(part + 2 * stride + off);
    s += *(const f32x4*)(part + 3 * stride + off);
    const float di = d[i];
    const f32x4 b = *(const f32x4*)(bias + c4);
    s = s * di + b;
    *(f32x4*)(out + off) = s;
}

extern "C" void kernel_launch(void* const* d_in, const int* in_sizes, int n_in,
                              void* d_out, int out_size, void* d_ws, size_t ws_size,
                              hipStream_t stream) {
    const float* A = (const float*)d_in[0];
    const float* X = (const float*)d_in[1];
    const float* W = (const float*)d_in[2];
    const float* bias = (const float*)d_in[3];
    const int* lp = (const int*)d_in[4];
    float* out = (float*)d_out;

    // workspace: d[8192] f32 | WT bf16[256*256] | ST bf16[256*8192] |
    //            part f32[4*8192*256] | Abf bf16[8192*8192]  (~164.2 MB)
    float* d = (float*)d_ws;
    unsigned short* WT = (unsigned short*)((char*)d_ws + 32768);
    unsigned short* ST = (unsigned short*)((char*)d_ws + 32768 + 131072);
    float* part = (float*)((char*)d_ws + 4358144);
    unsigned short* Abf = (unsigned short*)((char*)d_ws + 37912576);
    (void)ws_size;

    rowsum_conv<<<NN / 16, 256, 0, stream>>>(A, lp, d, Abf);
    wtrans_kernel<<<16, 256, 0, stream>>>(W, WT);
    support_kernel<<<NN / 16, 256, 0, stream>>>(X, WT, d, ST);
    main_gemm<<<128 * (NN / KCHUNK), 256, 0, stream>>>(Abf, ST, part);
    reduce_kernel<<<NN * DD / 4 / 256, 256, 0, stream>>>(part, d, bias, out);
}

// Round 2
// 464.968 us; speedup vs baseline: 1.0395x; 1.0154x over previous
//
#include <hip/hip_runtime.h>

// GCNConv: out = D^-1/2 (A) D^-1/2 (X @ W) + bias,  deg = rowsum(A) + l
// N=8192, DIN=DOUT=256. A fp32 [N][N], X fp32 [N][256], W fp32 [256][256].
//
// R6 -> R7 (k4 only):
//  * All in-loop vmem is now explicit: B-panel loads are inline-asm
//    global_load_dwordx4 (invisible to LLVM's waitcnt pass -> no conservative
//    vmcnt(0) drain before the MFMAs), A stays global_load_lds.
//  * Pipeline deepened to 2 iterations: 4-deep LDS ring for A, B issued 2
//    iters ahead into the register slot freed by this iter's compute (WAR:
//    issue strictly after all consuming MFMAs in program order).
//    Steady-state wait is vmcnt(10) = keep A(it+1)x2 + B(it+1)x8 in flight;
//    ~1240 cyc of cover > 900 cyc HBM-miss latency.
//  * XCD swizzle: kc=(bid&7)>>1, mt=((bid>>3)<<1)|(bid&1) -> each XCD's L2
//    holds exactly one 1 MB B-slice; same-CU block pairs share the B panel.
// Workspace: 32KB d | 128KB WT | 4MB ST | 32MB partials | 128MB A_bf16.

typedef __attribute__((ext_vector_type(8))) short short8;
typedef __attribute__((ext_vector_type(4))) float f32x4;

#define NN 8192
#define DD 256
#define KCHUNK 2048
#define BK 64
#define NITER (KCHUNK / BK)

// fp32 -> bf16 RNE (no NaN guard: inputs are finite)
__device__ inline unsigned short f2bfu(float x) {
    unsigned int u = __builtin_bit_cast(unsigned int, x);
    u += 0x7fffu + ((u >> 16) & 1u);
    return (unsigned short)(u >> 16);
}
__device__ inline unsigned int f2bf2u(float x, float y) {
    return (unsigned int)f2bfu(x) | ((unsigned int)f2bfu(y) << 16);
}
__device__ inline short8 cvt8(float4 a, float4 b) {
    union { unsigned int i[4]; short8 s; } u;
    u.i[0] = f2bf2u(a.x, a.y);
    u.i[1] = f2bf2u(a.z, a.w);
    u.i[2] = f2bf2u(b.x, b.y);
    u.i[3] = f2bf2u(b.z, b.w);
    return u.s;
}

__device__ inline void gload16(const void* g, void* l) {
    __builtin_amdgcn_global_load_lds(
        (const __attribute__((address_space(1))) unsigned int*)g,
        (__attribute__((address_space(3))) unsigned int*)l, 16, 0, 0);
}

// asm global load: invisible to the compiler's waitcnt accounting; retired
// only by our hand-placed s_waitcnt vmcnt(N).
#define BLOAD(dst, ptr, OFFSTR)                                        \
    asm volatile("global_load_dwordx4 %0, %1, off offset:" OFFSTR      \
                 : "=v"(dst) : "v"(ptr))

// ---------------- k1: rowsum -> d[i]; A -> bf16 swizzled tile image --------
__global__ __launch_bounds__(256) void rowsum_conv(const float* __restrict__ A,
                                                   const int* __restrict__ lp,
                                                   float* __restrict__ d,
                                                   unsigned short* __restrict__ Abf) {
    const int t = threadIdx.x;
    const int rl = t >> 4;     // row within block
    const int cg = t & 15;     // 16 threads per row
    const int i = blockIdx.x * 16 + rl;
    const int ti = i >> 6;
    const int rt = i & 63;
    const int swz = (rt & 7) << 4;

    const f32x4* Ar = (const f32x4*)(A + (size_t)i * NN);
    char* tb = (char*)Abf + (size_t)ti * 128 * 8192 + rt * 128 + ((8 * cg) ^ swz);

    float s0 = 0.f, s1 = 0.f;
#pragma unroll 4
    for (int k = 0; k < 128; ++k) {
        f32x4 v = __builtin_nontemporal_load(Ar + cg + 16 * k);  // nt: keep L3 for Abf
        s0 += v[0] + v[1];
        s1 += v[2] + v[3];
        *(uint2*)(tb + (size_t)k * 8192) =
            make_uint2(f2bf2u(v[0], v[1]), f2bf2u(v[2], v[3]));
    }
    float s = s0 + s1;
#pragma unroll
    for (int off = 8; off > 0; off >>= 1) s += __shfl_down(s, off, 16);
    if (cg == 0) {
        float deg = s + (float)(*lp);
        d[i] = deg > 0.f ? rsqrtf(deg) : 0.f;
    }
}

// ---------------- k2: W^T -> bf16 ----------------------------------------
__global__ __launch_bounds__(256) void wtrans_kernel(const float* __restrict__ W,
                                                     unsigned short* __restrict__ WT) {
    __shared__ unsigned short tile[64][65];
    const int tx = threadIdx.x & 63, ty = threadIdx.x >> 6;
    const int i0 = (blockIdx.x & 3) * 64;
    const int n0 = (blockIdx.x >> 2) * 64;
#pragma unroll
    for (int r = ty; r < 64; r += 4)
        tile[r][tx] = f2bfu(W[(size_t)(i0 + r) * DD + n0 + tx]);
    __syncthreads();
#pragma unroll
    for (int r = ty; r < 64; r += 4)
        WT[(size_t)(n0 + r) * DD + i0 + tx] = tile[tx][r];
}

// ---------------- k3: S_T[n][j] = bf16(d_j * (X@W)[j][n]) ----------------
__global__ __launch_bounds__(256) void support_kernel(const float* __restrict__ X,
                                                      const unsigned short* __restrict__ WT,
                                                      const float* __restrict__ d,
                                                      unsigned short* __restrict__ ST) {
    const int j0 = blockIdx.x * 16;
    const int lane = threadIdx.x & 63;
    const int w = threadIdx.x >> 6;
    const int q = lane >> 4;
    const int l15 = lane & 15;
    const int nb = w * 64;

    f32x4 acc[4];
#pragma unroll
    for (int b = 0; b < 4; ++b) acc[b] = (f32x4)(0.f);

    const float* Xbase = X + (size_t)(j0 + l15) * DD + q * 8;
    const unsigned short* Wbase = WT + (size_t)(nb + l15) * DD + q * 8;

#pragma unroll
    for (int k0 = 0; k0 < DD; k0 += 32) {
        const float4* p = (const float4*)(Xbase + k0);
        short8 afr = cvt8(p[0], p[1]);
        short8 bfr[4];
#pragma unroll
        for (int ni = 0; ni < 4; ++ni)
            bfr[ni] = *(const short8*)(Wbase + ni * 16 * DD + k0);
#pragma unroll
        for (int ni = 0; ni < 4; ++ni)
            acc[ni] = __builtin_amdgcn_mfma_f32_16x16x32_bf16(afr, bfr[ni], acc[ni], 0, 0, 0);
    }

    const int j0r = j0 + q * 4;
    float dj[4];
#pragma unroll
    for (int r = 0; r < 4; ++r) dj[r] = d[j0r + r];
#pragma unroll
    for (int ni = 0; ni < 4; ++ni) {
        const int n = nb + ni * 16 + l15;
        unsigned int lo = f2bf2u(acc[ni][0] * dj[0], acc[ni][1] * dj[1]);
        unsigned int hi = f2bf2u(acc[ni][2] * dj[2], acc[ni][3] * dj[3]);
        *(uint2*)(ST + (size_t)n * NN + j0r) = make_uint2(lo, hi);
    }
}

// ---------------- k4: partial[kc] = A_bf16 @ S_T^T -----------------------
// M=64, N=256, BK=64, KCHUNK=2048; 512 blocks (2/CU), depth-2 pipeline.
// Per iter: [vmcnt(10); s_barrier] | issue A(it+2)->LDS ring | compute(it)
// from LDS[it&3] + bfr[it&1] | issue B(it+2) into slot it&1 (just freed).
// vmcnt(10) == keep {A(it+1)x2, B(it+1)x8} in flight, retire A(it)/B(it).
__global__ __launch_bounds__(256, 2) void main_gemm(const unsigned short* __restrict__ Abf,
                                                    const unsigned short* __restrict__ ST,
                                                    float* __restrict__ part) {
    __shared__ __align__(16) unsigned short Abuf[4][4096];  // 4-deep ring, 32 KB

    const int bid = blockIdx.x;
    // XCD swizzle: bid%8 == XCD; 2 XCDs per kc -> 1 MB B-slice per L2.
    const int kc = (bid & 7) >> 1;          // 0..3
    const int mt = ((bid >> 3) << 1) | (bid & 1);  // 0..127
    const int tid = threadIdx.x;
    const int lane = tid & 63;
    const int w = tid >> 6;
    const int q = lane >> 4;
    const int l15 = lane & 15;
    const int nb = w * 64;
    const int swz = (l15 & 7) << 4;

    const char* Ag = (const char*)Abf + ((size_t)mt * 128 + kc * NITER) * 8192
                     + w * 2048 + lane * 16;

    // per-ni B base pointers (k-offset 0 of this kc chunk), advanced 128 B/iter
    const char* Pn[4];
#pragma unroll
    for (int ni = 0; ni < 4; ++ni)
        Pn[ni] = (const char*)ST +
                 ((size_t)(nb + l15 + ni * 16) * NN + (size_t)kc * KCHUNK + q * 8) * 2;

    f32x4 acc[4][4];
#pragma unroll
    for (int a = 0; a < 4; ++a)
#pragma unroll
        for (int b = 0; b < 4; ++b) acc[a][b] = (f32x4)(0.f);

    short8 bfr[2][2][4];  // [slot][kk2][ni]

    // ---- prologue: A0, B0, A1, B1 (this order is the vmcnt contract)
    {
        unsigned short* l0 = &Abuf[0][w * 1024];
        gload16(Ag, l0);
        gload16(Ag + 1024, l0 + 512);
    }
    __builtin_amdgcn_sched_barrier(0);
#pragma unroll
    for (int ni = 0; ni < 4; ++ni) {
        BLOAD(bfr[0][0][ni], Pn[ni], "0");
        BLOAD(bfr[0][1][ni], Pn[ni], "64");
    }
    __builtin_amdgcn_sched_barrier(0);
    {
        unsigned short* l1 = &Abuf[1][w * 1024];
        gload16(Ag + 8192, l1);
        gload16(Ag + 8192 + 1024, l1 + 512);
    }
    __builtin_amdgcn_sched_barrier(0);
#pragma unroll
    for (int ni = 0; ni < 4; ++ni) {
        BLOAD(bfr[1][0][ni], Pn[ni], "128");
        BLOAD(bfr[1][1][ni], Pn[ni], "192");
    }
    __builtin_amdgcn_sched_barrier(0);

    const char* AbBase = (const char*)&Abuf[0][0] + l15 * 128;

#pragma unroll 2
    for (int it = 0; it < NITER - 2; ++it) {
        // retire A(it)+B(it); keep A(it+1)x2 + B(it+1)x8 in flight
        __asm__ __volatile__("s_waitcnt vmcnt(10)\n\ts_barrier" ::: "memory");
        __builtin_amdgcn_sched_barrier(0);

        {  // issue A(it+2) into ring slot (it+2)&3
            const char* gn = Ag + (size_t)(it + 2) * 8192;
            unsigned short* ln = &Abuf[(it + 2) & 3][w * 1024];
            gload16(gn, ln);
            gload16(gn + 1024, ln + 512);
        }
        __builtin_amdgcn_sched_barrier(0);

        // compute(it): swizzled ds_read_b128 frags + register B slot it&1
        const char* Ab = AbBase + ((it & 3) << 13);
#pragma unroll
        for (int kk2 = 0; kk2 < 2; ++kk2) {
            short8 afr[4];
#pragma unroll
            for (int mi = 0; mi < 4; ++mi)
                afr[mi] = *(const short8*)(Ab + mi * 2048 + ((kk2 * 64 + q * 16) ^ swz));
#pragma unroll
            for (int mi = 0; mi < 4; ++mi)
#pragma unroll
                for (int ni = 0; ni < 4; ++ni)
                    acc[mi][ni] = __builtin_amdgcn_mfma_f32_16x16x32_bf16(
                        afr[mi], bfr[it & 1][kk2][ni], acc[mi][ni], 0, 0, 0);
        }
        __builtin_amdgcn_sched_barrier(0);

        // issue B(it+2) into slot it&1 (all consuming MFMAs already issued)
#pragma unroll
        for (int ni = 0; ni < 4; ++ni) {
            BLOAD(bfr[it & 1][0][ni], Pn[ni], "256");
            BLOAD(bfr[it & 1][1][ni], Pn[ni], "320");
        }
#pragma unroll
        for (int ni = 0; ni < 4; ++ni) Pn[ni] += 128;
        __builtin_amdgcn_sched_barrier(0);
    }

    // ---- peel it = NITER-2 (ring 2, slot 0)
    __asm__ __volatile__("s_waitcnt vmcnt(10)\n\ts_barrier" ::: "memory");
    __builtin_amdgcn_sched_barrier(0);
    {
        const char* Ab = AbBase + (((NITER - 2) & 3) << 13);
#pragma unroll
        for (int kk2 = 0; kk2 < 2; ++kk2) {
            short8 afr[4];
#pragma unroll
            for (int mi = 0; mi < 4; ++mi)
                afr[mi] = *(const short8*)(Ab + mi * 2048 + ((kk2 * 64 + q * 16) ^ swz));
#pragma unroll
            for (int mi = 0; mi < 4; ++mi)
#pragma unroll
                for (int ni = 0; ni < 4; ++ni)
                    acc[mi][ni] = __builtin_amdgcn_mfma_f32_16x16x32_bf16(
                        afr[mi], bfr[0][kk2][ni], acc[mi][ni], 0, 0, 0);
        }
    }
    // ---- peel it = NITER-1 (ring 3, slot 1)
    __asm__ __volatile__("s_waitcnt vmcnt(0)\n\ts_barrier" ::: "memory");
    __builtin_amdgcn_sched_barrier(0);
    {
        const char* Ab = AbBase + (((NITER - 1) & 3) << 13);
#pragma unroll
        for (int kk2 = 0; kk2 < 2; ++kk2) {
            short8 afr[4];
#pragma unroll
            for (int mi = 0; mi < 4; ++mi)
                afr[mi] = *(const short8*)(Ab + mi * 2048 + ((kk2 * 64 + q * 16) ^ swz));
#pragma unroll
            for (int mi = 0; mi < 4; ++mi)
#pragma unroll
                for (int ni = 0; ni < 4; ++ni)
                    acc[mi][ni] = __builtin_amdgcn_mfma_f32_16x16x32_bf16(
                        afr[mi], bfr[1][kk2][ni], acc[mi][ni], 0, 0, 0);
        }
    }

    // epilogue: plain stores of raw partials (d_i & bias applied in reduce)
    float* P = part + (size_t)kc * NN * DD;
#pragma unroll
    for (int mi = 0; mi < 4; ++mi) {
        const int r0 = mt * 64 + mi * 16 + q * 4;
#pragma unroll
        for (int ni = 0; ni < 4; ++ni) {
            const int n = nb + ni * 16 + l15;
#pragma unroll
            for (int rr = 0; rr < 4; ++rr)
                P[(size_t)(r0 + rr) * DD + n] = acc[mi][ni][rr];
        }
    }
}

// ---------------- k5: out = d_i * (p0+p1+p2+p3) + bias -------------------
__global__ __launch_bounds__(256) void reduce_kernel(const float* __restrict__ part,
                                                     const float* __restrict__ d,
                                                     const float* __restrict__ bias,
                                                     float* __restrict__ out) {
    const int idx = blockIdx.x * 256 + threadIdx.x;  // 0..524287
    const int i = idx >> 6;                          // row
    const int c4 = (idx & 63) << 2;                  // col (floats)
    const size_t off = (size_t)i * DD + c4;
    const size_t stride = (size_t)NN * DD;
    f32x4 s = *(const f32x4*)(part + off);
    s += *(const f32x4*)(part + stride + off);
    s += *(const f32x4*)(part + 2 * stride + off);
    s += *(const f32x4*)(part + 3 * stride + off);
    const float di = d[i];
    const f32x4 b = *(const f32x4*)(bias + c4);
    s = s * di + b;
    *(f32x4*)(out + off) = s;
}

extern "C" void kernel_launch(void* const* d_in, const int* in_sizes, int n_in,
                              void* d_out, int out_size, void* d_ws, size_t ws_size,
                              hipStream_t stream) {
    const float* A = (const float*)d_in[0];
    const float* X = (const float*)d_in[1];
    const float* W = (const float*)d_in[2];
    const float* bias = (const float*)d_in[3];
    const int* lp = (const int*)d_in[4];
    float* out = (float*)d_out;

    // workspace: d[8192] f32 | WT bf16[256*256] | ST bf16[256*8192] |
    //            part f32[4*8192*256] | Abf bf16[8192*8192]  (~164.2 MB)
    float* d = (float*)d_ws;
    unsigned short* WT = (unsigned short*)((char*)d_ws + 32768);
    unsigned short* ST = (unsigned short*)((char*)d_ws + 32768 + 131072);
    float* part = (float*)((char*)d_ws + 4358144);
    unsigned short* Abf = (unsigned short*)((char*)d_ws + 37912576);
    (void)ws_size;

    rowsum_conv<<<NN / 16, 256, 0, stream>>>(A, lp, d, Abf);
    wtrans_kernel<<<16, 256, 0, stream>>>(W, WT);
    support_kernel<<<NN / 16, 256, 0, stream>>>(X, WT, d, ST);
    main_gemm<<<128 * (NN / KCHUNK), 256, 0, stream>>>(Abf, ST, part);
    reduce_kernel<<<NN * DD / 4 / 256, 256, 0, stream>>>(part, d, bias, out);
}